// Round 8
// baseline (2412.085 us; speedup 1.0000x reference)
//
#include <hip/hip_runtime.h>
#include <hip/hip_bf16.h>
#include <math.h>

#define N_BATCH 2048
#define T_STEPS 50
#define NCODES  40
#define MH      526
#define AUXD    10
#define WLROWS  536    // MH + AUXD
#define E_DIM   256
#define G_DIM   1024   // 4*E
#define TCHUNK  10     // time steps per chunk (5 chunks)
#define MBLK    64     // (n,t) rows per fused block

typedef __attribute__((ext_vector_type(8))) short short8;   // 8 bf16 = 4 VGPR
typedef __attribute__((ext_vector_type(4))) short short4v;  // 4 bf16 = 2 VGPR
typedef __attribute__((ext_vector_type(4))) float f32x4;

__device__ __forceinline__ short f2bf(float f) {
    __hip_bfloat16 h = __float2bfloat16(f);
    return *reinterpret_cast<short*>(&h);
}
__device__ __forceinline__ float bf2f(unsigned short u) {
    return __uint_as_float(((unsigned int)u) << 16);
}
__device__ __forceinline__ float sigf(float x) {
    return 1.f / (1.f + __expf(-x));
}
__device__ __forceinline__ float tanhfast(float x) {
    return 2.f / (1.f + __expf(-2.f * x)) - 1.f;
}

// ---------------------------------------------------------------------------
// Zero the barrier counters (must run each launch; graph-replay safe).
// ---------------------------------------------------------------------------
__global__ __launch_bounds__(256) void k_zero(int* __restrict__ cnt)
{
    const int i = blockIdx.x * 256 + threadIdx.x;
    if (i < 5 * 64 * TCHUNK) cnt[i] = 0;
}

// ---------------------------------------------------------------------------
// Wrec: R pre-permuted into per-wave register-load order.
// fg = ((cs*4 + wE)*4 + g)*8 + kk ; dst[fg*512 + lane*8 + j]
//   = R[kk*32 + p*8 + j][g*256 + cs*64 + wE*16 + lr]
// ---------------------------------------------------------------------------
__global__ __launch_bounds__(256) void k_prep_wrec(
    const float* __restrict__ R, short* __restrict__ Wrec)
{
    const int gid  = blockIdx.x * 256 + threadIdx.x;   // 32768
    const int fg   = gid >> 6, lane = gid & 63;
    const int p    = lane >> 4, lr = lane & 15;
    const int kk   = fg & 7;
    const int g    = (fg >> 3) & 3;
    const int wE   = (fg >> 5) & 3;
    const int cs   = fg >> 7;
    const int n    = g * 256 + cs * 64 + wE * 16 + lr;
    short* dst = Wrec + (size_t)fg * 512 + lane * 8;
    #pragma unroll
    for (int j = 0; j < 8; ++j)
        dst[j] = f2bf(R[(size_t)(kk * 32 + p * 8 + j) * G_DIM + n]);
}

// WfK (K for k_fused phase 3): fg = (kb*8 + cb)*8 + w
__global__ __launch_bounds__(256) void k_prep_wfk(
    const float* __restrict__ K, short* __restrict__ WfK)
{
    const int gid  = blockIdx.x * 256 + threadIdx.x;   // 32768
    const int fg   = gid >> 6, lane = gid & 63;
    const int p    = lane >> 4, lr = lane & 15;
    const int kb   = fg >> 6;
    const int cb   = (fg >> 3) & 7;
    const int w    = fg & 7;
    const int n    = w * 128 + cb * 16 + lr;
    short* dst = WfK + (size_t)fg * 512 + lane * 8;
    #pragma unroll
    for (int j = 0; j < 8; ++j)
        dst[j] = f2bf(K[(size_t)(kb * 32 + p * 8 + j) * G_DIM + n]);
}

// WfL (W_lin for k_fused phase 2): fg = (kk*2 + cb)*8 + w, kk 0..16
__global__ __launch_bounds__(256) void k_prep_wfl(
    const float* __restrict__ W_lin, short* __restrict__ WfL)
{
    const int gid  = blockIdx.x * 256 + threadIdx.x;   // 17408
    const int fg   = gid >> 6, lane = gid & 63;
    const int p    = lane >> 4, lr = lane & 15;
    const int kk   = fg >> 4;
    const int cb   = (fg >> 3) & 1;
    const int w    = fg & 7;
    const int n    = w * 32 + cb * 16 + lr;
    short* dst = WfL + (size_t)fg * 512 + lane * 8;
    #pragma unroll
    for (int j = 0; j < 8; ++j) {
        const int k = kk * 32 + p * 8 + j;
        dst[j] = (k < WLROWS) ? f2bf(W_lin[(size_t)k * E_DIM + n]) : (short)0;
    }
}

// ---------------------------------------------------------------------------
// Fused embed + xz GEMM, tl-major, 64 rows/block (grid = TCHUNK*32).
// Output in k_rec fragment order:
//   idx = ((((rg32*TCHUNK+tl)*4 + cs)*4 + wE)*8 + rf*4 + g)*256 + lane*4
// ---------------------------------------------------------------------------
__global__ __launch_bounds__(512, 1) void k_fused(
    const int* __restrict__ code, const float* __restrict__ aux,
    const short* __restrict__ WfL, const float* __restrict__ b_lin,
    const short* __restrict__ WfK, short* __restrict__ xzp, int t0)
{
    const int tid  = threadIdx.x;
    const int w    = tid >> 6;
    const int lane = tid & 63;
    const int lr   = lane & 15;
    const int p    = lane >> 4;
    const int tl   = blockIdx.x >> 5;          // 0..TCHUNK-1
    const int ngg  = blockIdx.x & 31;
    const int n0   = ngg * MBLK;               // 64 consecutive batch rows
    const int t    = t0 + tl;

    __shared__ __align__(16) short oh[MBLK][552];   // 70.6 KB
    __shared__ __align__(16) short xs[MBLK][264];   // 33.8 KB

    for (int i = tid; i < (MBLK * 552) / 8; i += 512)
        ((int4*)&oh[0][0])[i] = (int4){0, 0, 0, 0};
    __syncthreads();

    for (int i = tid; i < MBLK * NCODES; i += 512) {
        const int r = i / NCODES;
        const int j = i - r * NCODES;
        const int c = code[((size_t)(n0 + r) * T_STEPS + t) * NCODES + j];
        if (c > 0) ((unsigned short*)&oh[0][0])[r * 552 + (c - 1)] = 0x3F80;
    }
    for (int i = tid; i < MBLK * AUXD; i += 512) {
        const int r = i / AUXD;
        const int a = i - r * AUXD;
        oh[r][MH + a] = f2bf(aux[((size_t)(n0 + r) * T_STEPS + t) * AUXD + a]);
    }
    __syncthreads();

    const short* wfl_thr = WfL + (size_t)w * 512 + lane * 8;
    const short* wfk_thr = WfK + (size_t)w * 512 + lane * 8;

    // ---- Phase 2: xs = relu(oh @ WfL^T + b_lin), wave cols w*32.. ----
    {
        f32x4 acc[4][2];
        #pragma unroll
        for (int rb = 0; rb < 4; ++rb)
            #pragma unroll
            for (int cb = 0; cb < 2; ++cb)
                acc[rb][cb] = (f32x4){0.f, 0.f, 0.f, 0.f};

        for (int kk = 0; kk < 17; ++kk) {
            short8 a[4];
            #pragma unroll
            for (int rb = 0; rb < 4; ++rb)
                a[rb] = *(const short8*)&oh[rb * 16 + lr][kk * 32 + p * 8];
            #pragma unroll
            for (int cb = 0; cb < 2; ++cb) {
                short8 bf = *(const short8*)(wfl_thr + (size_t)(kk * 2 + cb) * 4096);
                #pragma unroll
                for (int rb = 0; rb < 4; ++rb)
                    acc[rb][cb] = __builtin_amdgcn_mfma_f32_16x16x32_bf16(
                        a[rb], bf, acc[rb][cb], 0, 0, 0);
            }
        }
        float bias[2];
        #pragma unroll
        for (int cb = 0; cb < 2; ++cb) bias[cb] = b_lin[w * 32 + cb * 16 + lr];
        #pragma unroll
        for (int rb = 0; rb < 4; ++rb)
            #pragma unroll
            for (int cb = 0; cb < 2; ++cb)
                #pragma unroll
                for (int rr = 0; rr < 4; ++rr)
                    xs[rb * 16 + p * 4 + rr][w * 32 + cb * 16 + lr] =
                        f2bf(fmaxf(acc[rb][cb][rr] + bias[cb], 0.f));
        __syncthreads();
    }

    // ---- Phase 3: xz = xs @ WfK^T, two cb-halves, frag-order output ----
    #pragma unroll
    for (int half = 0; half < 2; ++half) {
        f32x4 acc[4][4];
        #pragma unroll
        for (int rb = 0; rb < 4; ++rb)
            #pragma unroll
            for (int c4 = 0; c4 < 4; ++c4)
                acc[rb][c4] = (f32x4){0.f, 0.f, 0.f, 0.f};

        for (int kb = 0; kb < 8; ++kb) {
            short8 a[4];
            #pragma unroll
            for (int rb = 0; rb < 4; ++rb)
                a[rb] = *(const short8*)&xs[rb * 16 + lr][kb * 32 + p * 8];
            #pragma unroll
            for (int c4 = 0; c4 < 4; ++c4) {
                const int cb = half * 4 + c4;
                short8 bf = *(const short8*)(wfk_thr + (size_t)(kb * 8 + cb) * 4096);
                #pragma unroll
                for (int rb = 0; rb < 4; ++rb)
                    acc[rb][c4] = __builtin_amdgcn_mfma_f32_16x16x32_bf16(
                        a[rb], bf, acc[rb][c4], 0, 0, 0);
            }
        }
        #pragma unroll
        for (int rb = 0; rb < 4; ++rb) {
            const int rg = ngg * 2 + (rb >> 1);   // global 32-row group
            const int rf = rb & 1;
            #pragma unroll
            for (int c4 = 0; c4 < 4; ++c4) {
                const int cb = half * 4 + c4;
                const int c0 = w * 128 + cb * 16;
                const int g  = c0 >> 8;
                const int rem = c0 & 255;
                const int cs = rem >> 6;
                const int wE = (rem >> 4) & 3;
                short4v v;
                #pragma unroll
                for (int rr = 0; rr < 4; ++rr) v[rr] = f2bf(acc[rb][c4][rr]);
                *(short4v*)(xzp +
                    ((((size_t)(rg * TCHUNK + tl) * 4 + cs) * 4 + wE) * 8 +
                     rf * 4 + g) * 256 + lane * 4) = v;
            }
        }
    }
}

// ---------------------------------------------------------------------------
// Recurrence v5: weights in REGISTERS (zero steady-state weight traffic).
// Grid 256 = cs(4) * 64 + rg(64). Block: 32 rows x 64 e-cols, 256 thr.
// Wave w: e-cols cs*64+w*16+lr, all 4 gates; bw[4][8] = 128 VGPR loaded once.
// Per step: MFMA from LDS-staged h (all 256 e), gates in reg, write own h
// slice to parity-buffered global h_buf, 4-block flag barrier, restage.
// Peers are same-XCD (blockIdx stride 64 ≡ 0 mod 8).
// ---------------------------------------------------------------------------
__global__ __launch_bounds__(256, 1) void k_rec(
    const short* __restrict__ xzp, const int* __restrict__ length,
    const short* __restrict__ Wrec, const float* __restrict__ b,
    short* __restrict__ h_buf, float* __restrict__ c_state,
    float* __restrict__ xlast, int* __restrict__ cnt, int t0)
{
    const int tid  = threadIdx.x;
    const int w    = tid >> 6;
    const int lane = tid & 63;
    const int lr   = lane & 15;
    const int p    = lane >> 4;
    const int rg   = blockIdx.x & 63;
    const int cs   = blockIdx.x >> 6;
    const int r0   = rg * 32;
    const int e    = cs * 64 + w * 16 + lr;

    __shared__ __align__(16) short h_L[2][8][512];   // 16 KB, XOR-swizzled
    __shared__ int s_len[32];

    if (tid < 32) s_len[tid] = length[r0 + tid];

    // ---- weights -> registers (once) ----
    short8 bw[4][8];
    const short* wbase = Wrec + (size_t)((cs * 4 + w) * 4) * 8 * 512 + lane * 8;
    #pragma unroll
    for (int g = 0; g < 4; ++g)
        #pragma unroll
        for (int kk = 0; kk < 8; ++kk)
            bw[g][kk] = *(const short8*)(wbase + (size_t)(g * 8 + kk) * 512);

    float bias[4];
    #pragma unroll
    for (int g = 0; g < 4; ++g) bias[g] = b[g * 256 + e];

    float creg[2][4];
    if (t0 == 0) {
        #pragma unroll
        for (int rf = 0; rf < 2; ++rf)
            #pragma unroll
            for (int rr = 0; rr < 4; ++rr) creg[rf][rr] = 0.f;
    } else {
        #pragma unroll
        for (int rf = 0; rf < 2; ++rf)
            #pragma unroll
            for (int rr = 0; rr < 4; ++rr)
                creg[rf][rr] = c_state[(size_t)(r0 + rf * 16 + p * 4 + rr) * 256 + e];
    }
    __syncthreads();

    int len_r[2][4];
    #pragma unroll
    for (int rf = 0; rf < 2; ++rf)
        #pragma unroll
        for (int rr = 0; rr < 4; ++rr)
            len_r[rf][rr] = s_len[rf * 16 + p * 4 + rr];

    // ---- prologue: stage h(t0) ----
    if (t0 == 0) {
        for (int i = tid; i < 1024; i += 256)
            ((int4*)h_L)[i] = (int4){0, 0, 0, 0};
    } else {
        const short* hb_r = h_buf + (size_t)(t0 & 1) * N_BATCH * 256 + (size_t)r0 * 256;
        #pragma unroll
        for (int it = 0; it < 4; ++it) {
            const int idx = tid + it * 256;
            const int row = idx >> 5, oct = idx & 31;
            short8 v = *(const short8*)(hb_r + row * 256 + oct * 8);
            const int kk = oct >> 2, pp = oct & 3;
            const int slot = (pp * 16 + (row & 15)) ^ kk;
            *(short8*)&h_L[row >> 4][kk][slot * 8] = v;
        }
    }
    __syncthreads();

    const short* xzb = xzp +
        (size_t)(((rg * TCHUNK) * 4 + cs) * 4 + w) * 8 * 256 + lane * 4;

    // prefetch xz for tl=0
    short4v xv[8];
    #pragma unroll
    for (int i = 0; i < 8; ++i)
        xv[i] = *(const short4v*)(xzb + i * 256);

    for (int tl = 0; tl < TCHUNK; ++tl) {
        const int t = t0 + tl;

        f32x4 acc[2][4];
        #pragma unroll
        for (int rf = 0; rf < 2; ++rf)
            #pragma unroll
            for (int g = 0; g < 4; ++g)
                #pragma unroll
                for (int rr = 0; rr < 4; ++rr)
                    acc[rf][g][rr] = bf2f((unsigned short)xv[rf * 4 + g][rr]);

        if (tl + 1 < TCHUNK) {
            #pragma unroll
            for (int i = 0; i < 8; ++i)
                xv[i] = *(const short4v*)(xzb + (size_t)(tl + 1) * 32768 + i * 256);
        }

        // h @ R : weights from registers, h from LDS
        #pragma unroll
        for (int kk = 0; kk < 8; ++kk) {
            short8 a0 = *(const short8*)&h_L[0][kk][(lane ^ kk) * 8];
            short8 a1 = *(const short8*)&h_L[1][kk][(lane ^ kk) * 8];
            #pragma unroll
            for (int g = 0; g < 4; ++g) {
                acc[0][g] = __builtin_amdgcn_mfma_f32_16x16x32_bf16(
                    a0, bw[g][kk], acc[0][g], 0, 0, 0);
                acc[1][g] = __builtin_amdgcn_mfma_f32_16x16x32_bf16(
                    a1, bw[g][kk], acc[1][g], 0, 0, 0);
            }
        }

        // gates in registers; write own h slice to parity buffer
        short* hb_w = h_buf + (size_t)((t + 1) & 1) * N_BATCH * 256;
        #pragma unroll
        for (int rf = 0; rf < 2; ++rf) {
            #pragma unroll
            for (int rr = 0; rr < 4; ++rr) {
                float zi = acc[rf][0][rr] + bias[0];
                float zf = acc[rf][1][rr] + bias[1];
                float zg = acc[rf][2][rr] + bias[2];
                float zo = acc[rf][3][rr] + bias[3];
                float ig = sigf(zi), fg = sigf(zf);
                float gg = tanhfast(zg), og = sigf(zo);
                float cc = fg * creg[rf][rr] + ig * gg;
                float hh = og * tanhfast(cc);
                creg[rf][rr] = cc;
                const int row = r0 + rf * 16 + p * 4 + rr;
                hb_w[(size_t)row * 256 + e] = f2bf(hh);
                if (t == len_r[rf][rr] - 1)
                    xlast[(size_t)row * 256 + e] = hh;
                if (tl == TCHUNK - 1)
                    c_state[(size_t)row * 256 + e] = cc;
            }
        }

        if (tl + 1 < TCHUNK) {
            __threadfence();
            __syncthreads();
            if (tid == 0) {
                int* flag = &cnt[rg * TCHUNK + tl];
                atomicAdd(flag, 1);
                while (__hip_atomic_load(flag, __ATOMIC_ACQUIRE,
                                         __HIP_MEMORY_SCOPE_AGENT) < 4)
                    __builtin_amdgcn_s_sleep(2);
            }
            __syncthreads();
            __threadfence();
            // restage h(t+1) from parity buffer
            const short* hb_r = h_buf + (size_t)((t + 1) & 1) * N_BATCH * 256 +
                                (size_t)r0 * 256;
            #pragma unroll
            for (int it = 0; it < 4; ++it) {
                const int idx = tid + it * 256;
                const int row = idx >> 5, oct = idx & 31;
                short8 v = *(const short8*)(hb_r + row * 256 + oct * 8);
                const int kk = oct >> 2, pp = oct & 3;
                const int slot = (pp * 16 + (row & 15)) ^ kk;
                *(short8*)&h_L[row >> 4][kk][slot * 8] = v;
            }
            __syncthreads();
        }
    }
}

// ---------------------------------------------------------------------------
// Head MLP + L2 normalize (unchanged).
// ---------------------------------------------------------------------------
__global__ __launch_bounds__(256) void k_head(
    const float* __restrict__ xlast,
    const float* __restrict__ W0, const float* __restrict__ b0,
    const float* __restrict__ W1, const float* __restrict__ b1,
    float* __restrict__ out)
{
    const int n = blockIdx.x;
    const int j = threadIdx.x;

    __shared__ __align__(16) float xsh[E_DIM];
    __shared__ __align__(16) float y0[E_DIM];
    __shared__ float part[4];

    xsh[j] = xlast[(size_t)n * E_DIM + j];
    __syncthreads();

    float acc = b0[j];
    for (int k4 = 0; k4 < E_DIM; k4 += 4) {
        float4 xv = *reinterpret_cast<const float4*>(&xsh[k4]);
        #pragma unroll
        for (int kk = 0; kk < 4; ++kk)
            acc += (&xv.x)[kk] * W0[(size_t)(k4 + kk) * E_DIM + j];
    }
    y0[j] = fmaxf(acc, 0.f);
    __syncthreads();

    acc = b1[j];
    for (int k4 = 0; k4 < E_DIM; k4 += 4) {
        float4 yv = *reinterpret_cast<const float4*>(&y0[k4]);
        #pragma unroll
        for (int kk = 0; kk < 4; ++kk)
            acc += (&yv.x)[kk] * W1[(size_t)(k4 + kk) * E_DIM + j];
    }

    float sq = acc * acc;
    #pragma unroll
    for (int off = 32; off > 0; off >>= 1)
        sq += __shfl_xor(sq, off, 64);
    if ((j & 63) == 0) part[j >> 6] = sq;
    __syncthreads();
    float total = part[0] + part[1] + part[2] + part[3];

    out[(size_t)n * E_DIM + j] = acc * rsqrtf(total);
}

// ---------------------------------------------------------------------------
extern "C" void kernel_launch(void* const* d_in, const int* in_sizes, int n_in,
                              void* d_out, int out_size, void* d_ws, size_t ws_size,
                              hipStream_t stream) {
    const int*   code   = (const int*)  d_in[0];
    const float* aux    = (const float*)d_in[1];
    const int*   length = (const int*)  d_in[2];
    // d_in[3] = is_training (ignored)
    const float* W_lin  = (const float*)d_in[4];
    const float* b_lin  = (const float*)d_in[5];
    const float* K      = (const float*)d_in[6];
    const float* R      = (const float*)d_in[7];
    const float* b      = (const float*)d_in[8];
    const float* W0     = (const float*)d_in[9];
    const float* b0     = (const float*)d_in[10];
    const float* W1     = (const float*)d_in[11];
    const float* b1     = (const float*)d_in[12];
    float* out = (float*)d_out;

    // workspace layout (bytes, 16B aligned); total ~49.6 MB
    char* ws = (char*)d_ws;
    short* Wrec    = (short*)(ws + 0);            //    524,288
    short* WfK     = (short*)(ws + 524288);       //    524,288
    short* WfL     = (short*)(ws + 1048576);      //    278,528
    float* xlast   = (float*)(ws + 1327104);      //  2,097,152
    float* c_state = (float*)(ws + 3424256);      //  2,097,152
    short* h_buf   = (short*)(ws + 5521408);      //  2,097,152 (2 parity bufs)
    int*   cnt     = (int*)  (ws + 7618560);      //     16,384
    short* xzp     = (short*)(ws + 7634944);      // 41,943,040

    k_zero     <<<13,  256, 0, stream>>>(cnt);
    k_prep_wrec<<<128, 256, 0, stream>>>(R, Wrec);
    k_prep_wfk <<<128, 256, 0, stream>>>(K, WfK);
    k_prep_wfl <<<68,  256, 0, stream>>>(W_lin, WfL);

    for (int c = 0; c < T_STEPS / TCHUNK; ++c) {
        const int t0 = c * TCHUNK;
        k_fused<<<TCHUNK * 32, 512, 0, stream>>>(
            code, aux, WfL, b_lin, WfK, xzp, t0);
        k_rec<<<256, 256, 0, stream>>>(xzp, length, Wrec, b,
                                       h_buf, c_state, xlast,
                                       cnt + c * 64 * TCHUNK, t0);
    }

    k_head<<<N_BATCH, 256, 0, stream>>>(xlast, W0, b0, W1, b1, out);
}

// Round 9
// 824.569 us; speedup vs baseline: 2.9253x; 2.9253x over previous
//
#include <hip/hip_runtime.h>
#include <hip/hip_bf16.h>
#include <math.h>

#define N_BATCH 2048
#define T_STEPS 50
#define NCODES  40
#define MH      526
#define AUXD    10
#define WLROWS  536    // MH + AUXD
#define E_DIM   256
#define G_DIM   1024   // 4*E
#define BM      16     // batch rows per recurrence block
#define TCHUNK  10     // time steps per chunk (5 chunks)
#define MBLK    64     // (n,t) rows per fused block

typedef __attribute__((ext_vector_type(8))) short short8;   // 8 bf16 = 4 VGPR
typedef __attribute__((ext_vector_type(4))) short short4v;  // 4 bf16 = 2 VGPR
typedef __attribute__((ext_vector_type(4))) float f32x4;

__device__ __forceinline__ short f2bf(float f) {
    __hip_bfloat16 h = __float2bfloat16(f);
    return *reinterpret_cast<short*>(&h);
}
__device__ __forceinline__ float bf2f(unsigned short u) {
    return __uint_as_float(((unsigned int)u) << 16);
}
__device__ __forceinline__ float sigf(float x) {
    return 1.f / (1.f + __expf(-x));
}
__device__ __forceinline__ float tanhfast(float x) {
    return 2.f / (1.f + __expf(-2.f * x)) - 1.f;
}

// ---------------------------------------------------------------------------
// Wrec: R pre-permuted into k_rec per-wave register-load order.
// fg = wc*32 + g*8 + kk ; Wrec[fg*512 + lane*8 + j]
//   = R[kk*32 + p*8 + j][g*256 + wc*16 + lr]   (lane = p*16 + lr)
// Per-wave slice (wc fixed) = 32 contiguous 1KB frag-groups = 32 KB.
// ---------------------------------------------------------------------------
__global__ __launch_bounds__(256) void k_prep_wrec(
    const float* __restrict__ R, short* __restrict__ Wrec)
{
    const int gid  = blockIdx.x * 256 + threadIdx.x;   // 32768
    const int fg   = gid >> 6, lane = gid & 63;
    const int p    = lane >> 4, lr = lane & 15;
    const int kk   = fg & 7;
    const int g    = (fg >> 3) & 3;
    const int wc   = fg >> 5;
    const int n    = g * 256 + wc * 16 + lr;
    short* dst = Wrec + (size_t)fg * 512 + lane * 8;
    #pragma unroll
    for (int j = 0; j < 8; ++j)
        dst[j] = f2bf(R[(size_t)(kk * 32 + p * 8 + j) * G_DIM + n]);
}

// WfK (K for k_fused phase 3): fg = (kb*8 + cb)*8 + w
__global__ __launch_bounds__(256) void k_prep_wfk(
    const float* __restrict__ K, short* __restrict__ WfK)
{
    const int gid  = blockIdx.x * 256 + threadIdx.x;   // 32768
    const int fg   = gid >> 6, lane = gid & 63;
    const int p    = lane >> 4, lr = lane & 15;
    const int kb   = fg >> 6;
    const int cb   = (fg >> 3) & 7;
    const int w    = fg & 7;
    const int n    = w * 128 + cb * 16 + lr;
    short* dst = WfK + (size_t)fg * 512 + lane * 8;
    #pragma unroll
    for (int j = 0; j < 8; ++j)
        dst[j] = f2bf(K[(size_t)(kb * 32 + p * 8 + j) * G_DIM + n]);
}

// WfL (W_lin for k_fused phase 2): fg = (kk*2 + cb)*8 + w, kk 0..16
__global__ __launch_bounds__(256) void k_prep_wfl(
    const float* __restrict__ W_lin, short* __restrict__ WfL)
{
    const int gid  = blockIdx.x * 256 + threadIdx.x;   // 17408
    const int fg   = gid >> 6, lane = gid & 63;
    const int p    = lane >> 4, lr = lane & 15;
    const int kk   = fg >> 4;
    const int cb   = (fg >> 3) & 1;
    const int w    = fg & 7;
    const int n    = w * 32 + cb * 16 + lr;
    short* dst = WfL + (size_t)fg * 512 + lane * 8;
    #pragma unroll
    for (int j = 0; j < 8; ++j) {
        const int k = kk * 32 + p * 8 + j;
        dst[j] = (k < WLROWS) ? f2bf(W_lin[(size_t)k * E_DIM + n]) : (short)0;
    }
}

// ---------------------------------------------------------------------------
// Fused embed + xz GEMM, tl-major, 64 rows/block (grid = TCHUNK*32).
// Output in k_rec fragment order:
//   idx = (((rgg*TCHUNK + tl)*16 + wc)*4 + g)*256 + lane*4
// where rgg = global 16-row group, wc = (col&255)>>4, g = col>>8.
// ---------------------------------------------------------------------------
__global__ __launch_bounds__(512, 1) void k_fused(
    const int* __restrict__ code, const float* __restrict__ aux,
    const short* __restrict__ WfL, const float* __restrict__ b_lin,
    const short* __restrict__ WfK, short* __restrict__ xzp, int t0)
{
    const int tid  = threadIdx.x;
    const int w    = tid >> 6;
    const int lane = tid & 63;
    const int lr   = lane & 15;
    const int p    = lane >> 4;
    const int tl   = blockIdx.x >> 5;          // 0..TCHUNK-1
    const int ngg  = blockIdx.x & 31;
    const int n0   = ngg * MBLK;               // 64 consecutive batch rows
    const int t    = t0 + tl;

    __shared__ __align__(16) short oh[MBLK][552];   // 70.6 KB
    __shared__ __align__(16) short xs[MBLK][264];   // 33.8 KB

    for (int i = tid; i < (MBLK * 552) / 8; i += 512)
        ((int4*)&oh[0][0])[i] = (int4){0, 0, 0, 0};
    __syncthreads();

    for (int i = tid; i < MBLK * NCODES; i += 512) {
        const int r = i / NCODES;
        const int j = i - r * NCODES;
        const int c = code[((size_t)(n0 + r) * T_STEPS + t) * NCODES + j];
        if (c > 0) ((unsigned short*)&oh[0][0])[r * 552 + (c - 1)] = 0x3F80;
    }
    for (int i = tid; i < MBLK * AUXD; i += 512) {
        const int r = i / AUXD;
        const int a = i - r * AUXD;
        oh[r][MH + a] = f2bf(aux[((size_t)(n0 + r) * T_STEPS + t) * AUXD + a]);
    }
    __syncthreads();

    const short* wfl_thr = WfL + (size_t)w * 512 + lane * 8;
    const short* wfk_thr = WfK + (size_t)w * 512 + lane * 8;

    // ---- Phase 2: xs = relu(oh @ WfL^T + b_lin), wave cols w*32.. ----
    {
        f32x4 acc[4][2];
        #pragma unroll
        for (int rb = 0; rb < 4; ++rb)
            #pragma unroll
            for (int cb = 0; cb < 2; ++cb)
                acc[rb][cb] = (f32x4){0.f, 0.f, 0.f, 0.f};

        for (int kk = 0; kk < 17; ++kk) {
            short8 a[4];
            #pragma unroll
            for (int rb = 0; rb < 4; ++rb)
                a[rb] = *(const short8*)&oh[rb * 16 + lr][kk * 32 + p * 8];
            #pragma unroll
            for (int cb = 0; cb < 2; ++cb) {
                short8 bf = *(const short8*)(wfl_thr + (size_t)(kk * 2 + cb) * 4096);
                #pragma unroll
                for (int rb = 0; rb < 4; ++rb)
                    acc[rb][cb] = __builtin_amdgcn_mfma_f32_16x16x32_bf16(
                        a[rb], bf, acc[rb][cb], 0, 0, 0);
            }
        }
        float bias[2];
        #pragma unroll
        for (int cb = 0; cb < 2; ++cb) bias[cb] = b_lin[w * 32 + cb * 16 + lr];
        #pragma unroll
        for (int rb = 0; rb < 4; ++rb)
            #pragma unroll
            for (int cb = 0; cb < 2; ++cb)
                #pragma unroll
                for (int rr = 0; rr < 4; ++rr)
                    xs[rb * 16 + p * 4 + rr][w * 32 + cb * 16 + lr] =
                        f2bf(fmaxf(acc[rb][cb][rr] + bias[cb], 0.f));
        __syncthreads();
    }

    // ---- Phase 3: xz = xs @ WfK^T, two cb-halves, frag-order output ----
    #pragma unroll
    for (int half = 0; half < 2; ++half) {
        f32x4 acc[4][4];
        #pragma unroll
        for (int rb = 0; rb < 4; ++rb)
            #pragma unroll
            for (int c4 = 0; c4 < 4; ++c4)
                acc[rb][c4] = (f32x4){0.f, 0.f, 0.f, 0.f};

        for (int kb = 0; kb < 8; ++kb) {
            short8 a[4];
            #pragma unroll
            for (int rb = 0; rb < 4; ++rb)
                a[rb] = *(const short8*)&xs[rb * 16 + lr][kb * 32 + p * 8];
            #pragma unroll
            for (int c4 = 0; c4 < 4; ++c4) {
                const int cb = half * 4 + c4;
                short8 bf = *(const short8*)(wfk_thr + (size_t)(kb * 8 + cb) * 4096);
                #pragma unroll
                for (int rb = 0; rb < 4; ++rb)
                    acc[rb][c4] = __builtin_amdgcn_mfma_f32_16x16x32_bf16(
                        a[rb], bf, acc[rb][c4], 0, 0, 0);
            }
        }
        #pragma unroll
        for (int rb = 0; rb < 4; ++rb) {
            const int rgg = ngg * 4 + rb;   // global 16-row group
            #pragma unroll
            for (int c4 = 0; c4 < 4; ++c4) {
                const int cb = half * 4 + c4;
                const int c0 = w * 128 + cb * 16;
                const int g  = c0 >> 8;
                const int wc = (c0 >> 4) & 15;
                short4v v;
                #pragma unroll
                for (int rr = 0; rr < 4; ++rr) v[rr] = f2bf(acc[rb][c4][rr]);
                *(short4v*)(xzp +
                    ((((size_t)rgg * TCHUNK + tl) * 16 + wc) * 4 + g) * 256 +
                    lane * 4) = v;
            }
        }
    }
}

// ---------------------------------------------------------------------------
// Recurrence v6: REGISTER-RESIDENT WEIGHTS, block-local (no cross-block sync).
// 128 blocks x 1024 thr (16 waves), BM=16 rows/block (block owns ALL 1024
// z-cols). Wave wc: e-cols wc*16+lr, all 4 gates; bw[4][8] = 128 VGPR of R,
// loaded ONCE per dispatch -> zero steady-state weight traffic.
// h in frag-major dbuf LDS (1 barrier/step); xz coalesced + prefetched.
// ---------------------------------------------------------------------------
__global__ __launch_bounds__(1024, 4) void k_rec(
    const short* __restrict__ xzp, const int* __restrict__ length,
    const short* __restrict__ Wrec, const float* __restrict__ b,
    short* __restrict__ h_state, float* __restrict__ c_state,
    float* __restrict__ xlast, int t0)
{
    const int tid  = threadIdx.x;
    const int wc   = tid >> 6;           // 0..15
    const int lane = tid & 63;
    const int lr   = lane & 15;
    const int p    = lane >> 4;
    const int rgg  = blockIdx.x;
    const int r0   = rgg * BM;

    __shared__ __align__(16) short h_f[2][8][512];  // [buf][kk][lane*8+j] 16KB
    __shared__ int s_len[BM];
    __shared__ int s_maxlen;

    if (tid < BM) s_len[tid] = length[r0 + tid];
    __syncthreads();
    if (tid == 0) {
        int m = 0;
        for (int r2 = 0; r2 < BM; ++r2) m = max(m, s_len[r2]);
        s_maxlen = m;
    }
    __syncthreads();
    const int mlen = s_maxlen;
    if (mlen <= t0) return;
    const int steps = min(TCHUNK, mlen - t0);

    const int e   = wc * 16 + lr;        // this thread's e-column
    const int kkw = e >> 5;              // h_f write slot
    const int law = ((e >> 3) & 3) * 16;
    const int jw  = e & 7;

    // ---- weights -> registers (once per dispatch) ----
    short8 bw[4][8];
    const short* wbase = Wrec + (size_t)(wc * 32) * 512 + lane * 8;
    #pragma unroll
    for (int g = 0; g < 4; ++g)
        #pragma unroll
        for (int kk = 0; kk < 8; ++kk)
            bw[g][kk] = *(const short8*)(wbase + (size_t)(g * 8 + kk) * 512);

    float bias[4];
    #pragma unroll
    for (int g = 0; g < 4; ++g) bias[g] = b[g * 256 + e];

    int len_r[4];
    #pragma unroll
    for (int rr = 0; rr < 4; ++rr) len_r[rr] = s_len[p * 4 + rr];

    float creg[4];
    if (t0 == 0) {
        for (int i = tid; i < 2048; i += 1024) ((int*)h_f)[i] = 0;  // buf 0
        #pragma unroll
        for (int rr = 0; rr < 4; ++rr) creg[rr] = 0.f;
    } else {
        #pragma unroll
        for (int rr = 0; rr < 4; ++rr) {
            const int row = r0 + p * 4 + rr;
            creg[rr] = c_state[(size_t)row * E_DIM + e];
            h_f[0][kkw][(law + p * 4 + rr) * 8 + jw] =
                h_state[(size_t)row * E_DIM + e];
        }
    }
    __syncthreads();

    const short* xzb = xzp +
        ((size_t)rgg * TCHUNK * 16 + wc) * 4 * 256 + lane * 4;

    // prefetch xz for tl=0
    short4v xv[4];
    #pragma unroll
    for (int g = 0; g < 4; ++g)
        xv[g] = *(const short4v*)(xzb + g * 256);

    int cur = 0;
    for (int tl = 0; tl < steps; ++tl) {
        const int t = t0 + tl;

        // acc init from prefetched xz
        f32x4 acc[4];
        #pragma unroll
        for (int g = 0; g < 4; ++g)
            #pragma unroll
            for (int rr = 0; rr < 4; ++rr)
                acc[g][rr] = bf2f((unsigned short)xv[g][rr]);

        // prefetch next tl
        if (tl + 1 < steps) {
            #pragma unroll
            for (int g = 0; g < 4; ++g)
                xv[g] = *(const short4v*)(xzb + (size_t)(tl + 1) * 16384 + g * 256);
        }

        // h @ R : weights from registers, h from LDS
        #pragma unroll
        for (int kk = 0; kk < 8; ++kk) {
            short8 a = *(const short8*)&h_f[cur][kk][lane * 8];
            #pragma unroll
            for (int g = 0; g < 4; ++g)
                acc[g] = __builtin_amdgcn_mfma_f32_16x16x32_bf16(
                    a, bw[g][kk], acc[g], 0, 0, 0);
        }

        // gates in registers; write new h into other LDS buffer
        #pragma unroll
        for (int rr = 0; rr < 4; ++rr) {
            float zi = acc[0][rr] + bias[0];
            float zf = acc[1][rr] + bias[1];
            float zg = acc[2][rr] + bias[2];
            float zo = acc[3][rr] + bias[3];
            float ig = sigf(zi), fg = sigf(zf);
            float gg = tanhfast(zg), og = sigf(zo);
            float cc = fg * creg[rr] + ig * gg;
            float hh = og * tanhfast(cc);
            creg[rr] = cc;
            const short hb = f2bf(hh);
            h_f[cur ^ 1][kkw][(law + p * 4 + rr) * 8 + jw] = hb;
            const int row = r0 + p * 4 + rr;
            if (t == len_r[rr] - 1)
                xlast[(size_t)row * E_DIM + e] = hh;
            if (tl == steps - 1) {
                h_state[(size_t)row * E_DIM + e] = hb;
                c_state[(size_t)row * E_DIM + e] = cc;
            }
        }
        cur ^= 1;
        __syncthreads();   // new h visible before next step's a-reads
    }
}

// ---------------------------------------------------------------------------
// Head MLP + L2 normalize (unchanged).
// ---------------------------------------------------------------------------
__global__ __launch_bounds__(256) void k_head(
    const float* __restrict__ xlast,
    const float* __restrict__ W0, const float* __restrict__ b0,
    const float* __restrict__ W1, const float* __restrict__ b1,
    float* __restrict__ out)
{
    const int n = blockIdx.x;
    const int j = threadIdx.x;

    __shared__ __align__(16) float xsh[E_DIM];
    __shared__ __align__(16) float y0[E_DIM];
    __shared__ float part[4];

    xsh[j] = xlast[(size_t)n * E_DIM + j];
    __syncthreads();

    float acc = b0[j];
    for (int k4 = 0; k4 < E_DIM; k4 += 4) {
        float4 xv = *reinterpret_cast<const float4*>(&xsh[k4]);
        #pragma unroll
        for (int kk = 0; kk < 4; ++kk)
            acc += (&xv.x)[kk] * W0[(size_t)(k4 + kk) * E_DIM + j];
    }
    y0[j] = fmaxf(acc, 0.f);
    __syncthreads();

    acc = b1[j];
    for (int k4 = 0; k4 < E_DIM; k4 += 4) {
        float4 yv = *reinterpret_cast<const float4*>(&y0[k4]);
        #pragma unroll
        for (int kk = 0; kk < 4; ++kk)
            acc += (&yv.x)[kk] * W1[(size_t)(k4 + kk) * E_DIM + j];
    }

    float sq = acc * acc;
    #pragma unroll
    for (int off = 32; off > 0; off >>= 1)
        sq += __shfl_xor(sq, off, 64);
    if ((j & 63) == 0) part[j >> 6] = sq;
    __syncthreads();
    float total = part[0] + part[1] + part[2] + part[3];

    out[(size_t)n * E_DIM + j] = acc * rsqrtf(total);
}

// ---------------------------------------------------------------------------
extern "C" void kernel_launch(void* const* d_in, const int* in_sizes, int n_in,
                              void* d_out, int out_size, void* d_ws, size_t ws_size,
                              hipStream_t stream) {
    const int*   code   = (const int*)  d_in[0];
    const float* aux    = (const float*)d_in[1];
    const int*   length = (const int*)  d_in[2];
    // d_in[3] = is_training (ignored)
    const float* W_lin  = (const float*)d_in[4];
    const float* b_lin  = (const float*)d_in[5];
    const float* K      = (const float*)d_in[6];
    const float* R      = (const float*)d_in[7];
    const float* b      = (const float*)d_in[8];
    const float* W0     = (const float*)d_in[9];
    const float* b0     = (const float*)d_in[10];
    const float* W1     = (const float*)d_in[11];
    const float* b1     = (const float*)d_in[12];
    float* out = (float*)d_out;

    // workspace layout (bytes, 16B aligned); total ~48.5 MB
    char* ws = (char*)d_ws;
    short* Wrec    = (short*)(ws + 0);            //    524,288
    short* WfK     = (short*)(ws + 524288);       //    524,288
    short* WfL     = (short*)(ws + 1048576);      //    278,528
    float* xlast   = (float*)(ws + 1327104);      //  2,097,152
    short* h_state = (short*)(ws + 3424256);      //  1,048,576
    float* c_state = (float*)(ws + 4472832);      //  2,097,152
    short* xzp     = (short*)(ws + 6569984);      // 41,943,040

    k_prep_wrec<<<128, 256, 0, stream>>>(R, Wrec);
    k_prep_wfk <<<128, 256, 0, stream>>>(K, WfK);
    k_prep_wfl <<<68,  256, 0, stream>>>(W_lin, WfL);

    for (int c = 0; c < T_STEPS / TCHUNK; ++c) {
        const int t0 = c * TCHUNK;
        k_fused<<<TCHUNK * 32, 512, 0, stream>>>(
            code, aux, WfL, b_lin, WfK, xzp, t0);
        k_rec<<<N_BATCH / BM, 1024, 0, stream>>>(xzp, length, Wrec, b,
                                                 h_state, c_state, xlast, t0);
    }

    k_head<<<N_BATCH, 256, 0, stream>>>(xlast, W0, b0, W1, b1, out);
}